// Round 10
// baseline (166.949 us; speedup 1.0000x reference)
//
#include <hip/hip_runtime.h>

#define NN 100000
#define NE 3200000
#define DIN 128
#define DHID 16
#define DOUT 2
#define NBUCK 391            // ceil(NN/256) buckets of 256 dst nodes
#define EPT 16               // edges per thread in hist/fill
#define BHT 1024             // threads in hist/fill blocks
#define EPB (BHT * EPT)      // 16384 edges per block
#define NBB ((NE + EPB - 1) / EPB)  // 196

// round-to-nearest-even f32 -> bf16 (bits)
__device__ __forceinline__ unsigned f2bf(float f) {
    unsigned u = __float_as_uint(f);
    return (u + 0x7FFFu + ((u >> 16) & 1u)) >> 16;
}
__device__ __forceinline__ float bflo(unsigned a) { return __uint_as_float(a << 16); }
__device__ __forceinline__ float bfhi(unsigned a) { return __uint_as_float(a & 0xFFFF0000u); }

// ---------------- bucket count zero ----------------
__global__ __launch_bounds__(512) void k_zero_b(int* __restrict__ bcount) {
    int t = threadIdx.x;
    if (t < NBUCK) bcount[t] = 0;
}

// ---------------- coarse bucket histogram (dst >> 8) ----------------
__global__ __launch_bounds__(BHT) void k_bhist(const int* __restrict__ dst,
                                               int* __restrict__ bcount) {
    __shared__ int h[NBUCK];
    int t = threadIdx.x;
    for (int i = t; i < NBUCK; i += BHT) h[i] = 0;
    __syncthreads();
    long long base = (long long)blockIdx.x * EPB;
#pragma unroll
    for (int k = 0; k < EPT; ++k) {
        long long e = base + (long long)k * BHT + t;
        if (e < NE) atomicAdd(&h[((unsigned)dst[e]) >> 8], 1);
    }
    __syncthreads();
    for (int i = t; i < NBUCK; i += BHT) {
        int c = h[i];
        if (c) atomicAdd(&bcount[i], c);
    }
}

// ---------------- scan 391 bucket counts ----------------
__global__ __launch_bounds__(512) void k_bscan(const int* __restrict__ bcount,
                                               int* __restrict__ bstart,
                                               int* __restrict__ bcursor) {
    __shared__ int sc[512];
    int t = threadIdx.x;
    int c = (t < NBUCK) ? bcount[t] : 0;
    sc[t] = c;
    __syncthreads();
    for (int off = 1; off < 512; off <<= 1) {
        int v = sc[t];
        int add = (t >= off) ? sc[t - off] : 0;
        __syncthreads();
        sc[t] = v + add;
        __syncthreads();
    }
    int excl = sc[t] - c;
    if (t <= NBUCK) bstart[t] = excl;  // bstart[NBUCK] == NE
    if (t < NBUCK) bcursor[t] = excl;
}

// ---------------- bucket the edges: packed = (dstLow<<24)|src ----------------
__global__ __launch_bounds__(BHT) void k_bfill(const int* __restrict__ src,
                                               const int* __restrict__ dst,
                                               int* __restrict__ bcursor,
                                               unsigned* __restrict__ packed) {
    __shared__ int h[NBUCK];     // local hist, then local cursor
    __shared__ int hbase[NBUCK]; // reserved global base per bucket
    int t = threadIdx.x;
    for (int i = t; i < NBUCK; i += BHT) h[i] = 0;
    __syncthreads();
    long long base = (long long)blockIdx.x * EPB;
    int ed[EPT], es[EPT];
#pragma unroll
    for (int k = 0; k < EPT; ++k) {
        long long e = base + (long long)k * BHT + t;
        if (e < NE) {
            ed[k] = dst[e];
            es[k] = src[e];
            atomicAdd(&h[((unsigned)ed[k]) >> 8], 1);
        } else {
            ed[k] = -1;
            es[k] = 0;
        }
    }
    __syncthreads();
    for (int i = t; i < NBUCK; i += BHT) {
        int c = h[i];
        hbase[i] = c ? atomicAdd(&bcursor[i], c) : 0;
    }
    __syncthreads();
    for (int i = t; i < NBUCK; i += BHT) h[i] = 0;
    __syncthreads();
#pragma unroll
    for (int k = 0; k < EPT; ++k) {
        if (ed[k] >= 0) {
            unsigned d = (unsigned)ed[k];
            int b = d >> 8;
            int off = atomicAdd(&h[b], 1);
            packed[hbase[b] + off] = ((d & 255u) << 24) | (unsigned)es[k];
        }
    }
}

// ---------------- per-bucket exact sort -> rowstart, dinv, esrc ----------------
__global__ __launch_bounds__(256) void k_pass2(const int* __restrict__ bstart,
                                               const unsigned* __restrict__ packed,
                                               int* __restrict__ rowstart,
                                               float* __restrict__ dinv,
                                               int* __restrict__ esrc) {
    __shared__ int h[256], sc[256], cur[256];
    int b = blockIdx.x;
    int t = threadIdx.x;
    int dst0 = b << 8;
    int ebeg = bstart[b];
    int eend = bstart[b + 1];
    h[t] = 0;
    __syncthreads();
    for (int p = ebeg + t; p < eend; p += 256)
        atomicAdd(&h[packed[p] >> 24], 1);
    __syncthreads();
    int c = h[t];
    sc[t] = c;
    __syncthreads();
    for (int off = 1; off < 256; off <<= 1) {
        int v = sc[t];
        int add = (t >= off) ? sc[t - off] : 0;
        __syncthreads();
        sc[t] = v + add;
        __syncthreads();
    }
    int gpos = ebeg + sc[t] - c;
    int v = dst0 + t;
    if (v < NN) {
        rowstart[v] = gpos;
        dinv[v] = rsqrtf((float)(c + 1));
    }
    cur[t] = gpos;
    if (b == 0 && t == 0) rowstart[NN] = NE;
    __syncthreads();
    for (int p = ebeg + t; p < eend; p += 256) {
        unsigned pk = packed[p];
        int pos = atomicAdd(&cur[pk >> 24], 1);
        esrc[pos] = (int)(pk & 0xFFFFFFu);
    }
}

// ---------------- layer 1 transform: 1 thread/node, NO LDS ----------------
// W1 accesses are wave-uniform (k, ch compile-time) -> scalar s_load path
// through K$ (W1 = 8 KB, cache-resident); zero LDS/VALU cost for W.
// x loaded in 2 halves of 16 float4 (64 VGPR live, deep MLP). All indices
// compile-time constant (rule #20; R6/R7 spill lesson).
__global__ __launch_bounds__(256) void k_mm1(const float* __restrict__ x,
                                             const float* __restrict__ W1,
                                             const float* __restrict__ dinv,
                                             unsigned* __restrict__ g1b) {
    int v = blockIdx.x * 256 + threadIdx.x;
    if (v >= NN) return;
    const float4* xr = (const float4*)(x + (size_t)v * DIN);
    float acc[16];
#pragma unroll
    for (int j = 0; j < 16; ++j) acc[j] = 0.f;
#define FMA1(XV, K)                                                   \
    {                                                                 \
        const float xv_ = (XV);                                       \
        const float4 wA = *(const float4*)(W1 + (K) * 16 + 0);        \
        const float4 wB = *(const float4*)(W1 + (K) * 16 + 4);        \
        const float4 wC = *(const float4*)(W1 + (K) * 16 + 8);        \
        const float4 wD = *(const float4*)(W1 + (K) * 16 + 12);       \
        acc[0] = fmaf(xv_, wA.x, acc[0]);                             \
        acc[1] = fmaf(xv_, wA.y, acc[1]);                             \
        acc[2] = fmaf(xv_, wA.z, acc[2]);                             \
        acc[3] = fmaf(xv_, wA.w, acc[3]);                             \
        acc[4] = fmaf(xv_, wB.x, acc[4]);                             \
        acc[5] = fmaf(xv_, wB.y, acc[5]);                             \
        acc[6] = fmaf(xv_, wB.z, acc[6]);                             \
        acc[7] = fmaf(xv_, wB.w, acc[7]);                             \
        acc[8] = fmaf(xv_, wC.x, acc[8]);                             \
        acc[9] = fmaf(xv_, wC.y, acc[9]);                             \
        acc[10] = fmaf(xv_, wC.z, acc[10]);                           \
        acc[11] = fmaf(xv_, wC.w, acc[11]);                           \
        acc[12] = fmaf(xv_, wD.x, acc[12]);                           \
        acc[13] = fmaf(xv_, wD.y, acc[13]);                           \
        acc[14] = fmaf(xv_, wD.z, acc[14]);                           \
        acc[15] = fmaf(xv_, wD.w, acc[15]);                           \
    }
#define FMA4(I)                \
    FMA1(X[I].x, (I) * 4 + 0)  \
    FMA1(X[I].y, (I) * 4 + 1)  \
    FMA1(X[I].z, (I) * 4 + 2)  \
    FMA1(X[I].w, (I) * 4 + 3)
    {   // half 1: k = 0..63
        float4 X[16];
#pragma unroll
        for (int i = 0; i < 16; ++i) X[i] = xr[i];
        FMA4(0) FMA4(1) FMA4(2) FMA4(3) FMA4(4) FMA4(5) FMA4(6) FMA4(7)
        FMA4(8) FMA4(9) FMA4(10) FMA4(11) FMA4(12) FMA4(13) FMA4(14) FMA4(15)
    }
    {   // half 2: k = 64..127
        float4 X[16];
#pragma unroll
        for (int i = 0; i < 16; ++i) X[i] = xr[16 + i];
#define FMA4B(I)                      \
    FMA1(X[I].x, 64 + (I) * 4 + 0)    \
    FMA1(X[I].y, 64 + (I) * 4 + 1)    \
    FMA1(X[I].z, 64 + (I) * 4 + 2)    \
    FMA1(X[I].w, 64 + (I) * 4 + 3)
        FMA4B(0) FMA4B(1) FMA4B(2) FMA4B(3) FMA4B(4) FMA4B(5) FMA4B(6) FMA4B(7)
        FMA4B(8) FMA4B(9) FMA4B(10) FMA4B(11) FMA4B(12) FMA4B(13) FMA4B(14) FMA4B(15)
#undef FMA4B
    }
#undef FMA4
#undef FMA1
    float dv = dinv[v];
    unsigned pk[8];
#pragma unroll
    for (int j = 0; j < 8; ++j)
        pk[j] = f2bf(acc[2 * j] * dv) | (f2bf(acc[2 * j + 1] * dv) << 16);
    uint4* gp = (uint4*)(g1b + (size_t)v * 8);
    gp[0] = make_uint4(pk[0], pk[1], pk[2], pk[3]);
    gp[1] = make_uint4(pk[4], pk[5], pk[6], pk[7]);
}

// ---------------- layer 1 gather + fused layer-2 transform ----------------
// 8 lanes/node; lane j owns channels 2j,2j+1. After the gather, each lane
// applies relu+b1 and its W2 rows, then 3 shfl_xor reduce -> g2.
__global__ __launch_bounds__(256) void k_gather1mm2(const int* __restrict__ rowstart,
                                                    const int* __restrict__ esrc,
                                                    const float* __restrict__ dinv,
                                                    const unsigned* __restrict__ G,
                                                    const float* __restrict__ b1,
                                                    const float* __restrict__ W2,
                                                    float* __restrict__ g2) {
    int t = blockIdx.x * 256 + threadIdx.x;
    int v = t >> 3;
    int j = t & 7;
    if (v >= NN) return;
    int beg = rowstart[v];
    int end = rowstart[v + 1];
    unsigned a = G[(v << 3) + j];  // self loop
    float c0 = bflo(a), c1 = bfhi(a);
    int p = beg;
    int n4 = beg + ((end - beg) & ~3);
    for (; p < n4; p += 4) {
        int u0 = esrc[p], u1 = esrc[p + 1], u2 = esrc[p + 2], u3 = esrc[p + 3];
        unsigned b0 = G[(u0 << 3) + j];
        unsigned b1w = G[(u1 << 3) + j];
        unsigned b2w = G[(u2 << 3) + j];
        unsigned b3w = G[(u3 << 3) + j];
        c0 += bflo(b0) + bflo(b1w) + bflo(b2w) + bflo(b3w);
        c1 += bfhi(b0) + bfhi(b1w) + bfhi(b2w) + bfhi(b3w);
    }
    for (; p < end; ++p) {
        unsigned b = G[(esrc[p] << 3) + j];
        c0 += bflo(b);
        c1 += bfhi(b);
    }
    float dv = dinv[v];
    // fused mm2: relu(out1 + b1) @ W2, partial over this lane's 2 channels
    float o0 = fmaxf(c0 * dv + b1[2 * j], 0.f);
    float o1 = fmaxf(c1 * dv + b1[2 * j + 1], 0.f);
    float p0 = o0 * W2[(2 * j) * 2 + 0] + o1 * W2[(2 * j + 1) * 2 + 0];
    float p1 = o0 * W2[(2 * j) * 2 + 1] + o1 * W2[(2 * j + 1) * 2 + 1];
    p0 += __shfl_xor(p0, 1); p0 += __shfl_xor(p0, 2); p0 += __shfl_xor(p0, 4);
    p1 += __shfl_xor(p1, 1); p1 += __shfl_xor(p1, 2); p1 += __shfl_xor(p1, 4);
    if (j == 0) {
        float2 w = make_float2(p0 * dv, p1 * dv);
        *(float2*)(g2 + (size_t)v * 2) = w;
    }
}

// ---------------- layer 2 gather: 8 lanes/node = 4 edge-slots x 2 ch -------
__global__ __launch_bounds__(256) void k_gather2(const int* __restrict__ rowstart,
                                                 const int* __restrict__ esrc,
                                                 const float* __restrict__ dinv,
                                                 const float* __restrict__ g2,
                                                 const float* __restrict__ b2,
                                                 float* __restrict__ out) {
    int t = blockIdx.x * 256 + threadIdx.x;
    int v = t >> 3;
    if (v >= NN) return;
    int lane = t & 7;
    int ch = lane & 1;
    int slot = lane >> 1;
    int beg = rowstart[v];
    int end = rowstart[v + 1];
    float acc = 0.0f;
    for (int p = beg + slot; p < end; p += 4)
        acc += g2[(esrc[p] << 1) + ch];
    acc += __shfl_xor(acc, 2);
    acc += __shfl_xor(acc, 4);  // all slots summed
    float o = (acc + g2[(v << 1) + ch]) * dinv[v] + b2[ch];
    float other = __shfl_xor(o, 1);
    float m = fmaxf(o, other);
    float lse = m + logf(expf(o - m) + expf(other - m));
    if (slot == 0) out[(v << 1) + ch] = o - lse;
}

extern "C" void kernel_launch(void* const* d_in, const int* in_sizes, int n_in,
                              void* d_out, int out_size, void* d_ws, size_t ws_size,
                              hipStream_t stream) {
    const float* x  = (const float*)d_in[0];
    const float* W1 = (const float*)d_in[1];
    const float* b1 = (const float*)d_in[2];
    const float* W2 = (const float*)d_in[3];
    const float* b2 = (const float*)d_in[4];
    const int* ei   = (const int*)d_in[5];
    const int* src = ei;
    const int* dst = ei + NE;

    // workspace (4B elems). packed (NE=12.8MB) is dead after k_pass2;
    // g1b (8NN uints = 3.2MB) aliases it. Stream order makes this safe.
    int* ws       = (int*)d_ws;
    int* bcount   = ws;                    // 400
    int* bstart   = ws + 400;              // 400 (uses NBUCK+1)
    int* bcursor  = ws + 800;              // 400
    int* rowstart = ws + 1200;             // NN+16
    float* dinv   = (float*)(ws + 1200 + NN + 16);    // NN
    int* esrc     = ws + 1200 + 2 * NN + 16;          // NE
    unsigned* packed = (unsigned*)(esrc + NE);        // NE
    unsigned* g1b = packed;                // 8*NN uints (aliases packed)
    float* g2     = (float*)(packed + NE); // 2*NN

    float* out = (float*)d_out;

    k_zero_b<<<1, 512, 0, stream>>>(bcount);
    k_bhist<<<NBB, BHT, 0, stream>>>(dst, bcount);
    k_bscan<<<1, 512, 0, stream>>>(bcount, bstart, bcursor);
    k_bfill<<<NBB, BHT, 0, stream>>>(src, dst, bcursor, packed);
    k_pass2<<<NBUCK, 256, 0, stream>>>(bstart, packed, rowstart, dinv, esrc);
    k_mm1<<<(NN + 255) / 256, 256, 0, stream>>>(x, W1, dinv, g1b);
    k_gather1mm2<<<(NN * 8 + 255) / 256, 256, 0, stream>>>(rowstart, esrc, dinv, g1b, b1, W2, g2);
    k_gather2<<<(NN * 8 + 255) / 256, 256, 0, stream>>>(rowstart, esrc, dinv, g2, b2, out);
}

// Round 11
// 139.283 us; speedup vs baseline: 1.1986x; 1.1986x over previous
//
#include <hip/hip_runtime.h>

#define NN 100000
#define NE 3200000
#define DIN 128
#define DHID 16
#define DOUT 2
#define NBUCK 391            // ceil(NN/256) buckets of 256 dst nodes
#define EPT 16               // edges per thread in hist/fill
#define BHT 1024             // threads in hist/fill blocks
#define EPB (BHT * EPT)      // 16384 edges per block
#define NBB ((NE + EPB - 1) / EPB)  // 196
#define P2CAP 10240          // LDS edge buffer in pass2 (40 KB); avg bucket 8184

// round-to-nearest-even f32 -> bf16 (bits)
__device__ __forceinline__ unsigned f2bf(float f) {
    unsigned u = __float_as_uint(f);
    return (u + 0x7FFFu + ((u >> 16) & 1u)) >> 16;
}
__device__ __forceinline__ float bflo(unsigned a) { return __uint_as_float(a << 16); }
__device__ __forceinline__ float bfhi(unsigned a) { return __uint_as_float(a & 0xFFFF0000u); }

// ---------------- bucket count zero ----------------
__global__ __launch_bounds__(512) void k_zero_b(int* __restrict__ bcount) {
    int t = threadIdx.x;
    if (t < NBUCK) bcount[t] = 0;
}

// ---------------- coarse bucket histogram (dst >> 8) ----------------
__global__ __launch_bounds__(BHT) void k_bhist(const int* __restrict__ dst,
                                               int* __restrict__ bcount) {
    __shared__ int h[NBUCK];
    int t = threadIdx.x;
    for (int i = t; i < NBUCK; i += BHT) h[i] = 0;
    __syncthreads();
    long long base = (long long)blockIdx.x * EPB;
#pragma unroll
    for (int k = 0; k < EPT; ++k) {
        long long e = base + (long long)k * BHT + t;
        if (e < NE) atomicAdd(&h[((unsigned)dst[e]) >> 8], 1);
    }
    __syncthreads();
    for (int i = t; i < NBUCK; i += BHT) {
        int c = h[i];
        if (c) atomicAdd(&bcount[i], c);
    }
}

// ---------------- scan 391 bucket counts ----------------
__global__ __launch_bounds__(512) void k_bscan(const int* __restrict__ bcount,
                                               int* __restrict__ bstart,
                                               int* __restrict__ bcursor) {
    __shared__ int sc[512];
    int t = threadIdx.x;
    int c = (t < NBUCK) ? bcount[t] : 0;
    sc[t] = c;
    __syncthreads();
    for (int off = 1; off < 512; off <<= 1) {
        int v = sc[t];
        int add = (t >= off) ? sc[t - off] : 0;
        __syncthreads();
        sc[t] = v + add;
        __syncthreads();
    }
    int excl = sc[t] - c;
    if (t <= NBUCK) bstart[t] = excl;  // bstart[NBUCK] == NE
    if (t < NBUCK) bcursor[t] = excl;
}

// ---------------- bucket the edges: packed = (dstLow<<24)|src ----------------
__global__ __launch_bounds__(BHT) void k_bfill(const int* __restrict__ src,
                                               const int* __restrict__ dst,
                                               int* __restrict__ bcursor,
                                               unsigned* __restrict__ packed) {
    __shared__ int h[NBUCK];     // local hist, then local cursor
    __shared__ int hbase[NBUCK]; // reserved global base per bucket
    int t = threadIdx.x;
    for (int i = t; i < NBUCK; i += BHT) h[i] = 0;
    __syncthreads();
    long long base = (long long)blockIdx.x * EPB;
    int ed[EPT], es[EPT];
#pragma unroll
    for (int k = 0; k < EPT; ++k) {
        long long e = base + (long long)k * BHT + t;
        if (e < NE) {
            ed[k] = dst[e];
            es[k] = src[e];
            atomicAdd(&h[((unsigned)ed[k]) >> 8], 1);
        } else {
            ed[k] = -1;
            es[k] = 0;
        }
    }
    __syncthreads();
    for (int i = t; i < NBUCK; i += BHT) {
        int c = h[i];
        hbase[i] = c ? atomicAdd(&bcursor[i], c) : 0;
    }
    __syncthreads();
    for (int i = t; i < NBUCK; i += BHT) h[i] = 0;
    __syncthreads();
#pragma unroll
    for (int k = 0; k < EPT; ++k) {
        if (ed[k] >= 0) {
            unsigned d = (unsigned)ed[k];
            int b = d >> 8;
            int off = atomicAdd(&h[b], 1);
            packed[hbase[b] + off] = ((d & 255u) << 24) | (unsigned)es[k];
        }
    }
}

// ---------------- per-bucket exact sort -> rowstart, dinv, esrc ----------------
// v2: whole bucket buffered in LDS (one global read of packed instead of two).
// Fallback to the global-read path if a bucket exceeds P2CAP (can't happen
// for this dataset's uniform dsts: mean 8184, sigma~90, cap 10240).
__global__ __launch_bounds__(256) void k_pass2(const int* __restrict__ bstart,
                                               const unsigned* __restrict__ packed,
                                               int* __restrict__ rowstart,
                                               float* __restrict__ dinv,
                                               int* __restrict__ esrc) {
    __shared__ unsigned ebuf[P2CAP];  // 40 KB
    __shared__ int h[256], sc[256], cur[256];
    int b = blockIdx.x;
    int t = threadIdx.x;
    int dst0 = b << 8;
    int ebeg = bstart[b];
    int eend = bstart[b + 1];
    int n = eend - ebeg;
    bool fits = (n <= P2CAP);
    h[t] = 0;
    __syncthreads();
    if (fits) {
        for (int i = t; i < n; i += 256) {
            unsigned pk = packed[ebeg + i];
            ebuf[i] = pk;
            atomicAdd(&h[pk >> 24], 1);
        }
    } else {
        for (int i = t; i < n; i += 256)
            atomicAdd(&h[packed[ebeg + i] >> 24], 1);
    }
    __syncthreads();
    int c = h[t];
    sc[t] = c;
    __syncthreads();
    for (int off = 1; off < 256; off <<= 1) {
        int v = sc[t];
        int add = (t >= off) ? sc[t - off] : 0;
        __syncthreads();
        sc[t] = v + add;
        __syncthreads();
    }
    int gpos = ebeg + sc[t] - c;
    int v = dst0 + t;
    if (v < NN) {
        rowstart[v] = gpos;
        dinv[v] = rsqrtf((float)(c + 1));
    }
    cur[t] = gpos;
    if (b == 0 && t == 0) rowstart[NN] = NE;
    __syncthreads();
    if (fits) {
        for (int i = t; i < n; i += 256) {
            unsigned pk = ebuf[i];
            int pos = atomicAdd(&cur[pk >> 24], 1);
            esrc[pos] = (int)(pk & 0xFFFFFFu);
        }
    } else {
        for (int i = t; i < n; i += 256) {
            unsigned pk = packed[ebeg + i];
            int pos = atomicAdd(&cur[pk >> 24], 1);
            esrc[pos] = (int)(pk & 0xFFFFFFu);
        }
    }
}

// ---------------- layer 1 transform: 4 lanes/node, 4 channels/lane ----------
// R4-verbatim (proven no-spill, ~24 us). Lane q loads x-row quarter
// [q*32,q*32+32); x broadcast within quad via DPP quad-perm; W row-chunk via
// broadcast ds_read_b128. Channels lane-owned; no cross-lane reduction.
// R9 lesson: 1-thread/node scalar-W variant is latency-bound (1.5 waves/SIMD,
// s_load chain) at 53 us — wave count beats per-wave efficiency here.
__global__ __launch_bounds__(256) void k_mm1(const float* __restrict__ x,
                                             const float* __restrict__ W1,
                                             const float* __restrict__ dinv,
                                             unsigned* __restrict__ g1b) {
    __shared__ float Ws[DIN * DHID];  // 8 KB
    for (int i = threadIdx.x; i < DIN * DHID; i += 256) Ws[i] = W1[i];
    __syncthreads();
    int t = blockIdx.x * 256 + threadIdx.x;
    int v = t >> 2;
    int q = threadIdx.x & 3;
    if (v >= NN) return;
    float4 xq[8];
    const float4* xr = (const float4*)(x + (size_t)v * DIN + q * 32);
#pragma unroll
    for (int i = 0; i < 8; ++i) xq[i] = xr[i];
    const float* xs = (const float*)xq;
    float acc0 = 0.f, acc1 = 0.f, acc2 = 0.f, acc3 = 0.f;
    // quad-perm broadcast from quad-lane QQ: dpp_ctrl = QQ * 0x55
#define QSTEP(QQ, CTRL)                                                          \
    _Pragma("unroll")                                                            \
    for (int k = 0; k < 32; ++k) {                                               \
        float xv = __int_as_float(                                               \
            __builtin_amdgcn_mov_dpp(__float_as_int(xs[k]), CTRL, 0xF, 0xF, false)); \
        const float4 w = *(const float4*)&Ws[(QQ * 32 + k) * DHID + q * 4];      \
        acc0 += xv * w.x; acc1 += xv * w.y; acc2 += xv * w.z; acc3 += xv * w.w;  \
    }
    QSTEP(0, 0x00)
    QSTEP(1, 0x55)
    QSTEP(2, 0xAA)
    QSTEP(3, 0xFF)
#undef QSTEP
    float dv = dinv[v];
    unsigned u0 = f2bf(acc0 * dv) | (f2bf(acc1 * dv) << 16);
    unsigned u1 = f2bf(acc2 * dv) | (f2bf(acc3 * dv) << 16);
    ((uint2*)(g1b + (size_t)v * 8))[q] = make_uint2(u0, u1);
}

// ---------------- layer 1 gather + fused layer-2 transform ----------------
// 8 lanes/node; lane j owns channels 2j,2j+1. After the gather, each lane
// applies relu+b1 and its W2 rows, then 3 shfl_xor reduce -> g2.
__global__ __launch_bounds__(256) void k_gather1mm2(const int* __restrict__ rowstart,
                                                    const int* __restrict__ esrc,
                                                    const float* __restrict__ dinv,
                                                    const unsigned* __restrict__ G,
                                                    const float* __restrict__ b1,
                                                    const float* __restrict__ W2,
                                                    float* __restrict__ g2) {
    int t = blockIdx.x * 256 + threadIdx.x;
    int v = t >> 3;
    int j = t & 7;
    if (v >= NN) return;
    int beg = rowstart[v];
    int end = rowstart[v + 1];
    unsigned a = G[(v << 3) + j];  // self loop
    float c0 = bflo(a), c1 = bfhi(a);
    int p = beg;
    int n4 = beg + ((end - beg) & ~3);
    for (; p < n4; p += 4) {
        int u0 = esrc[p], u1 = esrc[p + 1], u2 = esrc[p + 2], u3 = esrc[p + 3];
        unsigned b0 = G[(u0 << 3) + j];
        unsigned b1w = G[(u1 << 3) + j];
        unsigned b2w = G[(u2 << 3) + j];
        unsigned b3w = G[(u3 << 3) + j];
        c0 += bflo(b0) + bflo(b1w) + bflo(b2w) + bflo(b3w);
        c1 += bfhi(b0) + bfhi(b1w) + bfhi(b2w) + bfhi(b3w);
    }
    for (; p < end; ++p) {
        unsigned b = G[(esrc[p] << 3) + j];
        c0 += bflo(b);
        c1 += bfhi(b);
    }
    float dv = dinv[v];
    // fused mm2: relu(out1 + b1) @ W2, partial over this lane's 2 channels
    float o0 = fmaxf(c0 * dv + b1[2 * j], 0.f);
    float o1 = fmaxf(c1 * dv + b1[2 * j + 1], 0.f);
    float p0 = o0 * W2[(2 * j) * 2 + 0] + o1 * W2[(2 * j + 1) * 2 + 0];
    float p1 = o0 * W2[(2 * j) * 2 + 1] + o1 * W2[(2 * j + 1) * 2 + 1];
    p0 += __shfl_xor(p0, 1); p0 += __shfl_xor(p0, 2); p0 += __shfl_xor(p0, 4);
    p1 += __shfl_xor(p1, 1); p1 += __shfl_xor(p1, 2); p1 += __shfl_xor(p1, 4);
    if (j == 0) {
        float2 w = make_float2(p0 * dv, p1 * dv);
        *(float2*)(g2 + (size_t)v * 2) = w;
    }
}

// ---------------- layer 2 gather: 8 lanes/node = 4 edge-slots x 2 ch -------
__global__ __launch_bounds__(256) void k_gather2(const int* __restrict__ rowstart,
                                                 const int* __restrict__ esrc,
                                                 const float* __restrict__ dinv,
                                                 const float* __restrict__ g2,
                                                 const float* __restrict__ b2,
                                                 float* __restrict__ out) {
    int t = blockIdx.x * 256 + threadIdx.x;
    int v = t >> 3;
    if (v >= NN) return;
    int lane = t & 7;
    int ch = lane & 1;
    int slot = lane >> 1;
    int beg = rowstart[v];
    int end = rowstart[v + 1];
    float acc = 0.0f;
    for (int p = beg + slot; p < end; p += 4)
        acc += g2[(esrc[p] << 1) + ch];
    acc += __shfl_xor(acc, 2);
    acc += __shfl_xor(acc, 4);  // all slots summed
    float o = (acc + g2[(v << 1) + ch]) * dinv[v] + b2[ch];
    float other = __shfl_xor(o, 1);
    float m = fmaxf(o, other);
    float lse = m + logf(expf(o - m) + expf(other - m));
    if (slot == 0) out[(v << 1) + ch] = o - lse;
}

extern "C" void kernel_launch(void* const* d_in, const int* in_sizes, int n_in,
                              void* d_out, int out_size, void* d_ws, size_t ws_size,
                              hipStream_t stream) {
    const float* x  = (const float*)d_in[0];
    const float* W1 = (const float*)d_in[1];
    const float* b1 = (const float*)d_in[2];
    const float* W2 = (const float*)d_in[3];
    const float* b2 = (const float*)d_in[4];
    const int* ei   = (const int*)d_in[5];
    const int* src = ei;
    const int* dst = ei + NE;

    // workspace (4B elems). packed (NE=12.8MB) is dead after k_pass2;
    // g1b (8NN uints = 3.2MB) aliases it. Stream order makes this safe.
    int* ws       = (int*)d_ws;
    int* bcount   = ws;                    // 400
    int* bstart   = ws + 400;              // 400 (uses NBUCK+1)
    int* bcursor  = ws + 800;              // 400
    int* rowstart = ws + 1200;             // NN+16
    float* dinv   = (float*)(ws + 1200 + NN + 16);    // NN
    int* esrc     = ws + 1200 + 2 * NN + 16;          // NE
    unsigned* packed = (unsigned*)(esrc + NE);        // NE
    unsigned* g1b = packed;                // 8*NN uints (aliases packed)
    float* g2     = (float*)(packed + NE); // 2*NN

    float* out = (float*)d_out;

    k_zero_b<<<1, 512, 0, stream>>>(bcount);
    k_bhist<<<NBB, BHT, 0, stream>>>(dst, bcount);
    k_bscan<<<1, 512, 0, stream>>>(bcount, bstart, bcursor);
    k_bfill<<<NBB, BHT, 0, stream>>>(src, dst, bcursor, packed);
    k_pass2<<<NBUCK, 256, 0, stream>>>(bstart, packed, rowstart, dinv, esrc);
    k_mm1<<<(NN * 4 + 255) / 256, 256, 0, stream>>>(x, W1, dinv, g1b);
    k_gather1mm2<<<(NN * 8 + 255) / 256, 256, 0, stream>>>(rowstart, esrc, dinv, g1b, b1, W2, g2);
    k_gather2<<<(NN * 8 + 255) / 256, 256, 0, stream>>>(rowstart, esrc, dinv, g2, b2, out);
}